// Round 2
// baseline (559.837 us; speedup 1.0000x reference)
//
#include <hip/hip_runtime.h>
#include <hip/hip_bf16.h>

typedef unsigned short u16;
typedef unsigned int   u32;
typedef __attribute__((ext_vector_type(8))) short short8;   // 8 x bf16 bits (4 VGPR)
typedef __attribute__((ext_vector_type(4))) short short4v;  // 4 x bf16 bits (8 B)
typedef __attribute__((ext_vector_type(4))) float f32x4;    // MFMA 16x16 accumulator

// round-to-nearest-even f32 -> bf16 (finite inputs only)
__device__ __forceinline__ u16 f2bf(float f) {
  u32 u = __float_as_uint(f);
  u32 r = (u + 0x7fffu + ((u >> 16) & 1u)) >> 16;
  return (u16)r;
}
__device__ __forceinline__ float bf2f(u16 u) {
  union { u32 i; float f; } v; v.i = ((u32)u) << 16; return v.f;
}

// ---------------------------------------------------------------------------
// Weight pre-convert: qkv_w [768][256] fp32 -> bf16, proj_w [256][256] -> bf16
// ---------------------------------------------------------------------------
__global__ __launch_bounds__(256) void wcvt_kernel(
    const float* __restrict__ qkvw, const float* __restrict__ pw,
    u16* __restrict__ wq, u16* __restrict__ wp) {
  const int e = (blockIdx.x * 256 + threadIdx.x) * 4;  // 256 blocks -> 262144
  if (e < 196608) {
    const float4 v = *(const float4*)(qkvw + e);
    short4v o; o[0]=(short)f2bf(v.x); o[1]=(short)f2bf(v.y);
    o[2]=(short)f2bf(v.z); o[3]=(short)f2bf(v.w);
    *(short4v*)(wq + e) = o;
  } else {
    const int e2 = e - 196608;
    const float4 v = *(const float4*)(pw + e2);
    short4v o; o[0]=(short)f2bf(v.x); o[1]=(short)f2bf(v.y);
    o[2]=(short)f2bf(v.z); o[3]=(short)f2bf(v.w);
    *(short4v*)(wp + e2) = o;
  }
}

// ---------------------------------------------------------------------------
// CPB MLP: table[225][8] = relu(coords @ w1^T + b1) @ w2^T   (fp32 math)
// ---------------------------------------------------------------------------
__global__ __launch_bounds__(256) void cpb_kernel(
    const float* __restrict__ ct, const float* __restrict__ w1,
    const float* __restrict__ b1, const float* __restrict__ w2,
    float* __restrict__ table) {
  const int r = blockIdx.x;            // 0..224
  const int t = threadIdx.x;           // 0..255
  const int lane = t & 63, wave = t >> 6;
  const float c0 = ct[r * 2 + 0];
  const float c1 = ct[r * 2 + 1];
  float acc[8] = {0.f, 0.f, 0.f, 0.f, 0.f, 0.f, 0.f, 0.f};
  for (int j = t; j < 512; j += 256) {
    float hid = fmaxf(c0 * w1[j * 2] + c1 * w1[j * 2 + 1] + b1[j], 0.f);
#pragma unroll
    for (int hh = 0; hh < 8; ++hh) acc[hh] += hid * w2[hh * 512 + j];
  }
#pragma unroll
  for (int hh = 0; hh < 8; ++hh)
#pragma unroll
    for (int off = 1; off < 64; off <<= 1) acc[hh] += __shfl_xor(acc[hh], off);
  __shared__ float red[4][8];
  if (lane == 0)
#pragma unroll
    for (int hh = 0; hh < 8; ++hh) red[wave][hh] = acc[hh];
  __syncthreads();
  if (t < 8) table[r * 8 + t] = red[0][t] + red[1][t] + red[2][t] + red[3][t];
}

// ---------------------------------------------------------------------------
// bm[w][h][i*64+j] = 16*sigmoid(table[rel_idx[i*64+j]][h]) + mask[w][i*64+j]
// fp32 to preserve logit precision. 64*8*4096 floats = 8 MB.
// ---------------------------------------------------------------------------
__global__ __launch_bounds__(256) void bm_kernel(
    const float* __restrict__ table, const int* __restrict__ rel,
    const float* __restrict__ mask, float* __restrict__ bm) {
  const int g = blockIdx.x * 256 + threadIdx.x;   // 0..524287, 4 elems each
  const int w = g >> 13;
  const int h = (g >> 10) & 7;
  const int ij = (g & 1023) * 4;
  const float4 mv = *(const float4*)(mask + (size_t)w * 4096 + ij);
  float4 o;
  o.x = 16.f / (1.f + __expf(-table[rel[ij + 0] * 8 + h])) + mv.x;
  o.y = 16.f / (1.f + __expf(-table[rel[ij + 1] * 8 + h])) + mv.y;
  o.z = 16.f / (1.f + __expf(-table[rel[ij + 2] * 8 + h])) + mv.z;
  o.w = 16.f / (1.f + __expf(-table[rel[ij + 3] * 8 + h])) + mv.w;
  *(float4*)(bm + ((size_t)(w * 8 + h)) * 4096 + ij) = o;
}

// ---------------------------------------------------------------------------
// Fully fused per-window kernel: 1024 threads (16 waves), one block per window.
// Same LDS layout as the 8-wave version (144 KB, 1 block/CU) but 16 waves ->
// 4 waves/SIMD (occupancy 23.5% -> ~47%) to hide L2/LDS latency.
//   A: stage x[64][256] -> bf16 LDS (1 float4/thread)
//   B: QKV GEMM. wave=(wm,wn): wm=row-half (32 rows), wn=96 cols. Epilogue
//      normalizes q,k rows in-register, writes qn/kn + transposed V to LDS.
//   C: attention. wave=(h,rh): head h, row-half rh. S -> softmax (bm table)
//      -> P (wave-private LDS) -> PV -> o_lds.
//   D: proj. wave=(wm,wn): 32 rows x 32 cols, K=256, fp32 out.
// 4 __syncthreads per block.
// ---------------------------------------------------------------------------
__global__ __launch_bounds__(1024) void fused_kernel(
    const float* __restrict__ X,      // [131072][256] fp32
    const float* __restrict__ bm,     // [64][8][4096] fp32
    const float* __restrict__ lsc,    // [8] fp32
    const u16*  __restrict__ Wqb,     // [768][256] bf16
    const float* __restrict__ qb, const float* __restrict__ vbias,
    const u16*  __restrict__ Wpb,     // [256][256] bf16
    const float* __restrict__ pb,     // [256] fp32
    float* __restrict__ out) {        // [131072][256] fp32
  __shared__ __attribute__((aligned(16))) u16 sA[16896];  // x[8][64][32] -> o[64][264]
  __shared__ __attribute__((aligned(16))) u16 sB[36864];  // qn[8][64][32]+kn[8][64][32] -> P[16][32][72]
  __shared__ __attribute__((aligned(16))) u16 sV[18432];  // vt[8][32][72]

  const int bw = blockIdx.x;        // window 0..2047
  const int w  = bw & 63;           // mask window index
  const int tid  = threadIdx.x;
  const int wave = tid >> 6, lane = tid & 63;
  const int l15 = lane & 15, l4 = lane >> 4;

  // ---- Phase A: stage x -> bf16 sA[kf][row][32]
  {
    const int row = tid >> 4;       // 0..63
    const int c4  = tid & 15;
    const float* xrow = X + ((size_t)bw * 64 + row) * 256;
#pragma unroll
    for (int u = 0; u < 4; ++u) {
      const int col = u * 64 + c4 * 4;
      const int kf = col >> 5, co = col & 31;
      const float4 xv = *(const float4*)(xrow + col);
      short4v t4; t4[0]=(short)f2bf(xv.x); t4[1]=(short)f2bf(xv.y);
      t4[2]=(short)f2bf(xv.z); t4[3]=(short)f2bf(xv.w);
      *(short4v*)&sA[kf * 2048 + row * 32 + co] = t4;
    }
  }
  __syncthreads();

  // ---- Phase B: QKV GEMM: wave=(wm,wn): rows [wm*32,+32) x cols [wn*96,+96)
  {
    const int wm = wave & 1;
    const int wn = wave >> 1;       // 0..7
    f32x4 acc[2][6];
#pragma unroll
    for (int mi = 0; mi < 2; ++mi)
#pragma unroll
      for (int nj = 0; nj < 6; ++nj) acc[mi][nj] = (f32x4){0.f, 0.f, 0.f, 0.f};

#pragma unroll
    for (int kf = 0; kf < 8; ++kf) {
      short8 af[2];
#pragma unroll
      for (int mi = 0; mi < 2; ++mi)
        af[mi] = *(const short8*)&sA[kf * 2048 + (wm * 32 + mi * 16 + l15) * 32 + l4 * 8];
#pragma unroll
      for (int nj = 0; nj < 6; ++nj) {
        const short8 bf = *(const short8*)(
            Wqb + (size_t)(wn * 96 + nj * 16 + l15) * 256 + kf * 32 + l4 * 8);
#pragma unroll
        for (int mi = 0; mi < 2; ++mi)
          acc[mi][nj] = __builtin_amdgcn_mfma_f32_16x16x32_bf16(af[mi], bf, acc[mi][nj], 0, 0, 0);
      }
    }

    // epilogue: 3 chunks of 32 cols; each chunk entirely one (which, head)
#pragma unroll
    for (int t = 0; t < 3; ++t) {
      const int nbase = wn * 96 + t * 32;   // wave-uniform
      const int which = nbase >> 8;         // 0=Q 1=K 2=V
      const int h = (nbase >> 5) & 7;
      const int c = nbase & 255;
      if (which <= 1) {
        u16* dst = (which == 0 ? sB : sB + 16384) + h * 2048;
        const float b0 = (which == 0) ? qb[c + l15] : 0.f;
        const float b1 = (which == 0) ? qb[c + 16 + l15] : 0.f;
#pragma unroll
        for (int mi = 0; mi < 2; ++mi)
#pragma unroll
          for (int r = 0; r < 4; ++r) {
            const float v0 = acc[mi][2 * t][r] + b0;
            const float v1 = acc[mi][2 * t + 1][r] + b1;
            float ss = v0 * v0 + v1 * v1;
            ss += __shfl_xor(ss, 1); ss += __shfl_xor(ss, 2);
            ss += __shfl_xor(ss, 4); ss += __shfl_xor(ss, 8);
            const float inv = 1.f / fmaxf(sqrtf(ss), 1e-12f);
            const int m = wm * 32 + mi * 16 + l4 * 4 + r;
            dst[m * 32 + l15]      = f2bf(v0 * inv);
            dst[m * 32 + 16 + l15] = f2bf(v1 * inv);
          }
      } else {
        const float b0 = vbias[c + l15];
        const float b1 = vbias[c + 16 + l15];
        u16* dst = sV + h * 2304;
#pragma unroll
        for (int mi = 0; mi < 2; ++mi)
#pragma unroll
          for (int r = 0; r < 4; ++r) {
            const int m = wm * 32 + mi * 16 + l4 * 4 + r;
            dst[l15 * 72 + m]        = f2bf(acc[mi][2 * t][r] + b0);
            dst[(16 + l15) * 72 + m] = f2bf(acc[mi][2 * t + 1][r] + b1);
          }
      }
    }
  }
  __syncthreads();   // qn/kn/vt complete

  // ---- Phase C: attention. wave=(h,rh): head h = wave>>1, rows rh*32..+32
  {
    const int h  = wave >> 1;
    const int rh = wave & 1;
    short8 aq[2], bk[4];
#pragma unroll
    for (int i = 0; i < 2; ++i)
      aq[i] = *(const short8*)&sB[h * 2048 + (rh * 32 + i * 16 + l15) * 32 + l4 * 8];
#pragma unroll
    for (int j = 0; j < 4; ++j)
      bk[j] = *(const short8*)&sB[16384 + h * 2048 + (j * 16 + l15) * 32 + l4 * 8];

    f32x4 s[2][4];
#pragma unroll
    for (int i = 0; i < 2; ++i)
#pragma unroll
      for (int j = 0; j < 4; ++j) {
        const f32x4 z = {0.f, 0.f, 0.f, 0.f};
        s[i][j] = __builtin_amdgcn_mfma_f32_16x16x32_bf16(aq[i], bk[j], z, 0, 0, 0);
      }
    __syncthreads();   // all waves' q/k frags consumed -> sB reusable as P

    const float scale = expf(fminf(lsc[h], 4.60517018598809136804f));
    const float* bmrow = bm + ((size_t)(w * 8 + h)) * 4096;
    u16* pW = sB + wave * 2304;     // wave-private P [32][72]

#pragma unroll
    for (int i = 0; i < 2; ++i)
#pragma unroll
      for (int r = 0; r < 4; ++r) {
        const int ml = i * 16 + l4 * 4 + r;       // local P row
        const int m  = rh * 32 + ml;              // global q row
        float v0[4]; float mx = -3.0e38f;
#pragma unroll
        for (int j = 0; j < 4; ++j) {
          const int col = j * 16 + l15;
          const float sv = s[i][j][r] * scale + bmrow[m * 64 + col];
          v0[j] = sv; mx = fmaxf(mx, sv);
        }
        mx = fmaxf(mx, __shfl_xor(mx, 1)); mx = fmaxf(mx, __shfl_xor(mx, 2));
        mx = fmaxf(mx, __shfl_xor(mx, 4)); mx = fmaxf(mx, __shfl_xor(mx, 8));
        float sum = 0.f;
#pragma unroll
        for (int j = 0; j < 4; ++j) { v0[j] = __expf(v0[j] - mx); sum += v0[j]; }
        sum += __shfl_xor(sum, 1); sum += __shfl_xor(sum, 2);
        sum += __shfl_xor(sum, 4); sum += __shfl_xor(sum, 8);
        const float isum = 1.f / sum;
#pragma unroll
        for (int j = 0; j < 4; ++j)
          pW[ml * 72 + j * 16 + l15] = f2bf(v0[j] * isum);
      }
    // wave-internal RAW on pW ordered by lgkmcnt (proven pattern)

    // O = P @ V : 2 m-tiles x 2 d-tiles x 2 k-steps
    f32x4 oa[2][2];
#pragma unroll
    for (int i = 0; i < 2; ++i)
#pragma unroll
      for (int nb = 0; nb < 2; ++nb) oa[i][nb] = (f32x4){0.f, 0.f, 0.f, 0.f};
#pragma unroll
    for (int kb = 0; kb < 2; ++kb) {
      short8 pa[2];
#pragma unroll
      for (int i = 0; i < 2; ++i)
        pa[i] = *(const short8*)&pW[(i * 16 + l15) * 72 + kb * 32 + l4 * 8];
#pragma unroll
      for (int nb = 0; nb < 2; ++nb) {
        const short8 vb8 = *(const short8*)&sV[h * 2304 + (nb * 16 + l15) * 72 + kb * 32 + l4 * 8];
#pragma unroll
        for (int i = 0; i < 2; ++i)
          oa[i][nb] = __builtin_amdgcn_mfma_f32_16x16x32_bf16(pa[i], vb8, oa[i][nb], 0, 0, 0);
      }
    }
#pragma unroll
    for (int i = 0; i < 2; ++i)
#pragma unroll
      for (int nb = 0; nb < 2; ++nb)
#pragma unroll
        for (int r = 0; r < 4; ++r) {
          const int m = rh * 32 + i * 16 + l4 * 4 + r;
          sA[m * 264 + h * 32 + nb * 16 + l15] = f2bf(oa[i][nb][r]);
        }
  }
  __syncthreads();   // o complete across all waves

  // ---- Phase D: proj. wave=(wm,wn): rows [wm*32,+32) x cols [wn*32,+32)
  {
    const int wm = wave & 1;
    const int n0 = (wave >> 1) * 32;
    f32x4 pacc[2][2];
#pragma unroll
    for (int mi = 0; mi < 2; ++mi)
#pragma unroll
      for (int nj = 0; nj < 2; ++nj) pacc[mi][nj] = (f32x4){0.f, 0.f, 0.f, 0.f};
#pragma unroll
    for (int k0 = 0; k0 < 256; k0 += 32) {
      short8 afr[2];
#pragma unroll
      for (int mi = 0; mi < 2; ++mi)
        afr[mi] = *(const short8*)&sA[(wm * 32 + mi * 16 + l15) * 264 + k0 + l4 * 8];
#pragma unroll
      for (int nj = 0; nj < 2; ++nj) {
        const short8 bfr = *(const short8*)(
            Wpb + (size_t)(n0 + nj * 16 + l15) * 256 + k0 + l4 * 8);
#pragma unroll
        for (int mi = 0; mi < 2; ++mi)
          pacc[mi][nj] = __builtin_amdgcn_mfma_f32_16x16x32_bf16(afr[mi], bfr, pacc[mi][nj], 0, 0, 0);
      }
    }
    float* orow = out + (size_t)bw * 64 * 256;
#pragma unroll
    for (int mi = 0; mi < 2; ++mi)
#pragma unroll
      for (int nj = 0; nj < 2; ++nj) {
        const int n = n0 + nj * 16 + l15;
        const float bias = pb[n];
#pragma unroll
        for (int r = 0; r < 4; ++r) {
          const int m = wm * 32 + mi * 16 + l4 * 4 + r;
          orow[(size_t)m * 256 + n] = pacc[mi][nj][r] + bias;
        }
      }
  }
}

// ---------------------------------------------------------------------------
// ws layout: [0,16K) table | [256K,640K) Wqkv bf16 | [704K,832K) Wproj bf16 |
// [1M, 9M) bm fp32.
// ---------------------------------------------------------------------------
extern "C" void kernel_launch(void* const* d_in, const int* in_sizes, int n_in,
                              void* d_out, int out_size, void* d_ws, size_t ws_size,
                              hipStream_t stream) {
  (void)in_sizes; (void)n_in; (void)out_size; (void)ws_size;
  const float* x    = (const float*)d_in[0];
  const float* mask = (const float*)d_in[1];
  const float* qkvw = (const float*)d_in[2];
  const float* qb   = (const float*)d_in[3];
  const float* vb   = (const float*)d_in[4];
  const float* lsc  = (const float*)d_in[5];
  const float* w1   = (const float*)d_in[6];
  const float* b1   = (const float*)d_in[7];
  const float* w2   = (const float*)d_in[8];
  const float* pw   = (const float*)d_in[9];
  const float* pb   = (const float*)d_in[10];
  const float* ct   = (const float*)d_in[11];
  const int* rel    = (const int*)d_in[12];
  float* out = (float*)d_out;

  char* ws = (char*)d_ws;
  float* table = (float*)(ws);
  u16* Wqb = (u16*)(ws + 262144);   // 393,216 B
  u16* Wpb = (u16*)(ws + 720896);   // 131,072 B
  float* bm = (float*)(ws + (1 << 20));  // 8 MB

  wcvt_kernel<<<256, 256, 0, stream>>>(qkvw, pw, Wqb, Wpb);
  cpb_kernel<<<225, 256, 0, stream>>>(ct, w1, b1, w2, table);
  bm_kernel<<<2048, 256, 0, stream>>>(table, rel, mask, bm);
  fused_kernel<<<2048, 1024, 0, stream>>>(x, bm, lsc, Wqb, qb, vb,
                                          Wpb, pb, out);
}

// Round 3
// 498.630 us; speedup vs baseline: 1.1227x; 1.1227x over previous
//
#include <hip/hip_runtime.h>
#include <hip/hip_bf16.h>

typedef unsigned short u16;
typedef unsigned int   u32;
typedef __attribute__((ext_vector_type(8))) short short8;   // 8 x bf16 bits (4 VGPR)
typedef __attribute__((ext_vector_type(4))) short short4v;  // 4 x bf16 bits (8 B)
typedef __attribute__((ext_vector_type(4))) float f32x4;    // MFMA 16x16 accumulator

// round-to-nearest-even f32 -> bf16 (finite inputs only)
__device__ __forceinline__ u16 f2bf(float f) {
  u32 u = __float_as_uint(f);
  u32 r = (u + 0x7fffu + ((u >> 16) & 1u)) >> 16;
  return (u16)r;
}

// ---------------------------------------------------------------------------
// Weight pre-convert: qkv_w [768][256] fp32 -> bf16, proj_w [256][256] -> bf16
// ---------------------------------------------------------------------------
__global__ __launch_bounds__(256) void wcvt_kernel(
    const float* __restrict__ qkvw, const float* __restrict__ pw,
    u16* __restrict__ wq, u16* __restrict__ wp) {
  const int e = (blockIdx.x * 256 + threadIdx.x) * 4;  // 256 blocks -> 262144
  if (e < 196608) {
    const float4 v = *(const float4*)(qkvw + e);
    short4v o; o[0]=(short)f2bf(v.x); o[1]=(short)f2bf(v.y);
    o[2]=(short)f2bf(v.z); o[3]=(short)f2bf(v.w);
    *(short4v*)(wq + e) = o;
  } else {
    const int e2 = e - 196608;
    const float4 v = *(const float4*)(pw + e2);
    short4v o; o[0]=(short)f2bf(v.x); o[1]=(short)f2bf(v.y);
    o[2]=(short)f2bf(v.z); o[3]=(short)f2bf(v.w);
    *(short4v*)(wp + e2) = o;
  }
}

// ---------------------------------------------------------------------------
// CPB MLP: table[225][8] = relu(coords @ w1^T + b1) @ w2^T   (fp32 math)
// ---------------------------------------------------------------------------
__global__ __launch_bounds__(256) void cpb_kernel(
    const float* __restrict__ ct, const float* __restrict__ w1,
    const float* __restrict__ b1, const float* __restrict__ w2,
    float* __restrict__ table) {
  const int r = blockIdx.x;            // 0..224
  const int t = threadIdx.x;           // 0..255
  const int lane = t & 63, wave = t >> 6;
  const float c0 = ct[r * 2 + 0];
  const float c1 = ct[r * 2 + 1];
  float acc[8] = {0.f, 0.f, 0.f, 0.f, 0.f, 0.f, 0.f, 0.f};
  for (int j = t; j < 512; j += 256) {
    float hid = fmaxf(c0 * w1[j * 2] + c1 * w1[j * 2 + 1] + b1[j], 0.f);
#pragma unroll
    for (int hh = 0; hh < 8; ++hh) acc[hh] += hid * w2[hh * 512 + j];
  }
#pragma unroll
  for (int hh = 0; hh < 8; ++hh)
#pragma unroll
    for (int off = 1; off < 64; off <<= 1) acc[hh] += __shfl_xor(acc[hh], off);
  __shared__ float red[4][8];
  if (lane == 0)
#pragma unroll
    for (int hh = 0; hh < 8; ++hh) red[wave][hh] = acc[hh];
  __syncthreads();
  if (t < 8) table[r * 8 + t] = red[0][t] + red[1][t] + red[2][t] + red[3][t];
}

// ---------------------------------------------------------------------------
// bmP[w][h][m][l][j] = 16*sigmoid(table[rel[m*64 + j*16+l]][h]) + mask[w][m][j*16+l]
// Permuted so a softmax lane (l15) reads its 4 values as ONE float4.
// fp32, 64*8*64*64 = 8 MB.
// ---------------------------------------------------------------------------
__global__ __launch_bounds__(256) void bm_kernel(
    const float* __restrict__ table, const int* __restrict__ rel,
    const float* __restrict__ mask, float* __restrict__ bmP) {
  const int g = blockIdx.x * 256 + threadIdx.x;   // 0..524287
  const int w = g >> 13;
  const int h = (g >> 10) & 7;
  const int m = (g >> 4) & 63;
  const int l = g & 15;
  float4 o;
#pragma unroll
  for (int j = 0; j < 4; ++j) {
    const int c = j * 16 + l;
    const float t = table[rel[m * 64 + c] * 8 + h];
    o[j] = 16.f / (1.f + __expf(-t)) + mask[(size_t)w * 4096 + m * 64 + c];
  }
  *(float4*)(bmP + ((((size_t)w * 8 + h) * 64 + m) * 64 + l * 4)) = o;
}

// ---------------------------------------------------------------------------
// Fully fused per-window kernel: 512 threads (8 waves), one block per window.
// LDS 144 KB -> 1 block/CU, so VGPRs are free up to 256: __launch_bounds__
// (512,2) + explicit software pipelining of all global (L2) loads.
//   A: stage x[64][256] -> bf16 LDS
//   B: QKV GEMM, wave owns 96 cols x 64 rows; B-frags from L2, PIPELINED
//      (preload kf+1 while MFMAing kf). Epilogue: in-register q/k row norm,
//      writes qn/kn + transposed V to LDS.
//   C: wave-per-head attention; bmP float4 bias+mask loads issued BEFORE
//      the S-MFMA cluster (latency hidden under MFMA).
//   D: proj GEMM from o_lds, weight frags PIPELINED across k0 steps.
// 4 __syncthreads per block.
// ---------------------------------------------------------------------------
__global__ __launch_bounds__(512, 2) void fused_kernel(
    const float* __restrict__ X,      // [131072][256] fp32
    const float* __restrict__ bmP,    // [64][8][64][64] fp32 (permuted)
    const float* __restrict__ lsc,    // [8] fp32
    const u16*  __restrict__ Wqb,     // [768][256] bf16
    const float* __restrict__ qb, const float* __restrict__ vbias,
    const u16*  __restrict__ Wpb,     // [256][256] bf16
    const float* __restrict__ pb,     // [256] fp32
    float* __restrict__ out) {        // [131072][256] fp32
  __shared__ __attribute__((aligned(16))) u16 sA[16896];  // x[8][64][32] -> o[64][264]
  __shared__ __attribute__((aligned(16))) u16 sB[36864];  // qn[8][64][32]+kn[8][64][32] -> P[8][64][72]
  __shared__ __attribute__((aligned(16))) u16 sV[18432];  // vt[8][32][72]

  const int bw = blockIdx.x;        // window 0..2047
  const int w  = bw & 63;           // mask window index
  const int tid  = threadIdx.x;
  const int wave = tid >> 6, lane = tid & 63;
  const int l15 = lane & 15, l4 = lane >> 4;

  // ---- Phase A: stage x -> bf16 sA[kf][row][32]
  {
    const int cq  = tid & 7;        // 8 chunks of 4 fp32 = 32 cols
    const int rlo = tid >> 3;       // 0..63
    const float* xrow = X + ((size_t)bw * 64 + rlo) * 256;
#pragma unroll
    for (int kf = 0; kf < 8; ++kf) {
      const float4 xv = *(const float4*)(xrow + kf * 32 + cq * 4);
      short4v t4; t4[0]=(short)f2bf(xv.x); t4[1]=(short)f2bf(xv.y);
      t4[2]=(short)f2bf(xv.z); t4[3]=(short)f2bf(xv.w);
      *(short4v*)&sA[kf * 2048 + rlo * 32 + cq * 4] = t4;
    }
  }
  __syncthreads();

  // ---- Phase B: QKV GEMM: rows 0..63 x cols [wave*96, wave*96+96), K=256
  {
    const u16* wbase = Wqb + (size_t)(wave * 96 + l15) * 256 + l4 * 8;
    f32x4 acc[4][6];
#pragma unroll
    for (int mi = 0; mi < 4; ++mi)
#pragma unroll
      for (int nj = 0; nj < 6; ++nj) acc[mi][nj] = (f32x4){0.f, 0.f, 0.f, 0.f};

    short8 bf_cur[6];
#pragma unroll
    for (int nj = 0; nj < 6; ++nj)
      bf_cur[nj] = *(const short8*)(wbase + (size_t)(nj * 16) * 256);

#pragma unroll
    for (int kf = 0; kf < 8; ++kf) {
      short8 af[4];
#pragma unroll
      for (int mi = 0; mi < 4; ++mi)
        af[mi] = *(const short8*)&sA[kf * 2048 + (mi * 16 + l15) * 32 + l4 * 8];
      short8 bf_nxt[6];
      if (kf < 7) {
#pragma unroll
        for (int nj = 0; nj < 6; ++nj)
          bf_nxt[nj] = *(const short8*)(wbase + (size_t)(nj * 16) * 256 + (kf + 1) * 32);
      }
#pragma unroll
      for (int nj = 0; nj < 6; ++nj)
#pragma unroll
        for (int mi = 0; mi < 4; ++mi)
          acc[mi][nj] = __builtin_amdgcn_mfma_f32_16x16x32_bf16(af[mi], bf_cur[nj], acc[mi][nj], 0, 0, 0);
      if (kf < 7) {
#pragma unroll
        for (int nj = 0; nj < 6; ++nj) bf_cur[nj] = bf_nxt[nj];
      }
    }

    // epilogue: 3 head-chunks of 32 cols each; head fully inside one wave.
#pragma unroll
    for (int t = 0; t < 3; ++t) {
      const int nbase = wave * 96 + t * 32;   // wave-uniform
      const int which = nbase >> 8;           // 0=Q 1=K 2=V
      const int h = (nbase >> 5) & 7;
      const int c = nbase & 255;
      if (which <= 1) {
        // normalize rows: 32 cols = 2 accum tiles x 16 lanes (l15)
        u16* dst = (which == 0 ? sB : sB + 16384) + h * 2048;
        const float b0 = (which == 0) ? qb[c + l15] : 0.f;
        const float b1 = (which == 0) ? qb[c + 16 + l15] : 0.f;
#pragma unroll
        for (int mi = 0; mi < 4; ++mi)
#pragma unroll
          for (int r = 0; r < 4; ++r) {
            const float v0 = acc[mi][2 * t][r] + b0;
            const float v1 = acc[mi][2 * t + 1][r] + b1;
            float ss = v0 * v0 + v1 * v1;
            ss += __shfl_xor(ss, 1); ss += __shfl_xor(ss, 2);
            ss += __shfl_xor(ss, 4); ss += __shfl_xor(ss, 8);
            const float inv = 1.f / fmaxf(sqrtf(ss), 1e-12f);
            const int m = mi * 16 + l4 * 4 + r;
            dst[m * 32 + l15]      = f2bf(v0 * inv);
            dst[m * 32 + 16 + l15] = f2bf(v1 * inv);
          }
      } else {
        // V: add bias, write transposed vt[h][d][token]
        const float b0 = vbias[c + l15];
        const float b1 = vbias[c + 16 + l15];
        u16* dst = sV + h * 2304;
#pragma unroll
        for (int mi = 0; mi < 4; ++mi)
#pragma unroll
          for (int r = 0; r < 4; ++r) {
            const int m = mi * 16 + l4 * 4 + r;
            dst[l15 * 72 + m]        = f2bf(acc[mi][2 * t][r] + b0);
            dst[(16 + l15) * 72 + m] = f2bf(acc[mi][2 * t + 1][r] + b1);
          }
      }
    }
  }
  __syncthreads();   // qn/kn/vt complete

  // ---- Phase C: attention, wave == head
  {
    const int h = wave;
    // bias+mask float4 loads issued FIRST (independent of S) to hide L2/L3
    const float* bmbase = bmP + (((size_t)(w * 8 + h)) * 64) * 64 + l15 * 4;
    float4 bmv[4][4];
#pragma unroll
    for (int i = 0; i < 4; ++i)
#pragma unroll
      for (int r = 0; r < 4; ++r) {
        const int m = i * 16 + l4 * 4 + r;
        bmv[i][r] = *(const float4*)(bmbase + (size_t)m * 64);
      }

    short8 aq[4], bk[4];
#pragma unroll
    for (int i = 0; i < 4; ++i)
      aq[i] = *(const short8*)&sB[h * 2048 + (i * 16 + l15) * 32 + l4 * 8];
#pragma unroll
    for (int j = 0; j < 4; ++j)
      bk[j] = *(const short8*)&sB[16384 + h * 2048 + (j * 16 + l15) * 32 + l4 * 8];

    f32x4 s[4][4];
#pragma unroll
    for (int i = 0; i < 4; ++i)
#pragma unroll
      for (int j = 0; j < 4; ++j) {
        const f32x4 z = {0.f, 0.f, 0.f, 0.f};
        s[i][j] = __builtin_amdgcn_mfma_f32_16x16x32_bf16(aq[i], bk[j], z, 0, 0, 0);
      }
    __syncthreads();   // all waves' q/k frags loaded -> sB reusable as P

    const float scale = expf(fminf(lsc[h], 4.60517018598809136804f));
    u16* pW = sB + wave * 4608;     // wave-private P [64][72]

#pragma unroll
    for (int i = 0; i < 4; ++i)
#pragma unroll
      for (int r = 0; r < 4; ++r) {
        const int m = i * 16 + l4 * 4 + r;
        float v0[4]; float mx = -3.0e38f;
#pragma unroll
        for (int j = 0; j < 4; ++j) {
          const float sv = s[i][j][r] * scale + bmv[i][r][j];
          v0[j] = sv; mx = fmaxf(mx, sv);
        }
        mx = fmaxf(mx, __shfl_xor(mx, 1)); mx = fmaxf(mx, __shfl_xor(mx, 2));
        mx = fmaxf(mx, __shfl_xor(mx, 4)); mx = fmaxf(mx, __shfl_xor(mx, 8));
        float sum = 0.f;
#pragma unroll
        for (int j = 0; j < 4; ++j) { v0[j] = __expf(v0[j] - mx); sum += v0[j]; }
        sum += __shfl_xor(sum, 1); sum += __shfl_xor(sum, 2);
        sum += __shfl_xor(sum, 4); sum += __shfl_xor(sum, 8);
        const float isum = 1.f / sum;
#pragma unroll
        for (int j = 0; j < 4; ++j)
          pW[m * 72 + j * 16 + l15] = f2bf(v0[j] * isum);
      }
    // wave-internal RAW on pW ordered by lgkmcnt (proven pattern)

    // O = P @ V : 4 m-tiles x 2 d-tiles x 2 k-steps
    f32x4 oa[4][2];
#pragma unroll
    for (int i = 0; i < 4; ++i)
#pragma unroll
      for (int nb = 0; nb < 2; ++nb) oa[i][nb] = (f32x4){0.f, 0.f, 0.f, 0.f};
#pragma unroll
    for (int kb = 0; kb < 2; ++kb) {
      short8 pa[4];
#pragma unroll
      for (int i = 0; i < 4; ++i)
        pa[i] = *(const short8*)&pW[(i * 16 + l15) * 72 + kb * 32 + l4 * 8];
#pragma unroll
      for (int nb = 0; nb < 2; ++nb) {
        const short8 vb8 = *(const short8*)&sV[h * 2304 + (nb * 16 + l15) * 72 + kb * 32 + l4 * 8];
#pragma unroll
        for (int i = 0; i < 4; ++i)
          oa[i][nb] = __builtin_amdgcn_mfma_f32_16x16x32_bf16(pa[i], vb8, oa[i][nb], 0, 0, 0);
      }
    }
#pragma unroll
    for (int i = 0; i < 4; ++i)
#pragma unroll
      for (int nb = 0; nb < 2; ++nb)
#pragma unroll
        for (int r = 0; r < 4; ++r) {
          const int m = i * 16 + l4 * 4 + r;
          sA[m * 264 + h * 32 + nb * 16 + l15] = f2bf(oa[i][nb][r]);
        }
  }
  __syncthreads();   // o complete across all waves

  // ---- Phase D: proj. wave owns output cols [wave*32, wave*32+32), K=256
  {
    const int n0 = wave * 32;
    const u16* pbase = Wpb + (size_t)(n0 + l15) * 256 + l4 * 8;
    f32x4 pacc[4][2];
#pragma unroll
    for (int mi = 0; mi < 4; ++mi)
#pragma unroll
      for (int nj = 0; nj < 2; ++nj) pacc[mi][nj] = (f32x4){0.f, 0.f, 0.f, 0.f};

    short8 bfr_cur[2];
#pragma unroll
    for (int nj = 0; nj < 2; ++nj)
      bfr_cur[nj] = *(const short8*)(pbase + (size_t)(nj * 16) * 256);

#pragma unroll
    for (int ks = 0; ks < 8; ++ks) {
      const int k0 = ks * 32;
      short8 afr[4];
#pragma unroll
      for (int mi = 0; mi < 4; ++mi)
        afr[mi] = *(const short8*)&sA[(mi * 16 + l15) * 264 + k0 + l4 * 8];
      short8 bfr_nxt[2];
      if (ks < 7) {
#pragma unroll
        for (int nj = 0; nj < 2; ++nj)
          bfr_nxt[nj] = *(const short8*)(pbase + (size_t)(nj * 16) * 256 + k0 + 32);
      }
#pragma unroll
      for (int nj = 0; nj < 2; ++nj)
#pragma unroll
        for (int mi = 0; mi < 4; ++mi)
          pacc[mi][nj] = __builtin_amdgcn_mfma_f32_16x16x32_bf16(afr[mi], bfr_cur[nj], pacc[mi][nj], 0, 0, 0);
      if (ks < 7) {
#pragma unroll
        for (int nj = 0; nj < 2; ++nj) bfr_cur[nj] = bfr_nxt[nj];
      }
    }
    float* orow = out + (size_t)bw * 64 * 256;
#pragma unroll
    for (int mi = 0; mi < 4; ++mi)
#pragma unroll
      for (int nj = 0; nj < 2; ++nj) {
        const int n = n0 + nj * 16 + l15;
        const float bias = pb[n];
#pragma unroll
        for (int r = 0; r < 4; ++r) {
          const int m = mi * 16 + l4 * 4 + r;
          orow[(size_t)m * 256 + n] = pacc[mi][nj][r] + bias;
        }
      }
  }
}

// ---------------------------------------------------------------------------
// ws layout: [0,16K) table | [256K,640K) Wqkv bf16 | [704K,832K) Wproj bf16 |
// [1M, 9M) bmP fp32.
// ---------------------------------------------------------------------------
extern "C" void kernel_launch(void* const* d_in, const int* in_sizes, int n_in,
                              void* d_out, int out_size, void* d_ws, size_t ws_size,
                              hipStream_t stream) {
  (void)in_sizes; (void)n_in; (void)out_size; (void)ws_size;
  const float* x    = (const float*)d_in[0];
  const float* mask = (const float*)d_in[1];
  const float* qkvw = (const float*)d_in[2];
  const float* qb   = (const float*)d_in[3];
  const float* vb   = (const float*)d_in[4];
  const float* lsc  = (const float*)d_in[5];
  const float* w1   = (const float*)d_in[6];
  const float* b1   = (const float*)d_in[7];
  const float* w2   = (const float*)d_in[8];
  const float* pw   = (const float*)d_in[9];
  const float* pb   = (const float*)d_in[10];
  const float* ct   = (const float*)d_in[11];
  const int* rel    = (const int*)d_in[12];
  float* out = (float*)d_out;

  char* ws = (char*)d_ws;
  float* table = (float*)(ws);
  u16* Wqb = (u16*)(ws + 262144);   // 393,216 B
  u16* Wpb = (u16*)(ws + 720896);   // 131,072 B
  float* bmP = (float*)(ws + (1 << 20));  // 8 MB

  wcvt_kernel<<<256, 256, 0, stream>>>(qkvw, pw, Wqb, Wpb);
  cpb_kernel<<<225, 256, 0, stream>>>(ct, w1, b1, w2, table);
  bm_kernel<<<2048, 256, 0, stream>>>(table, rel, mask, bmP);
  fused_kernel<<<2048, 512, 0, stream>>>(x, bmP, lsc, Wqb, qb, vb,
                                         Wpb, pb, out);
}

// Round 4
// 472.895 us; speedup vs baseline: 1.1838x; 1.0544x over previous
//
#include <hip/hip_runtime.h>
#include <hip/hip_bf16.h>

typedef unsigned short u16;
typedef unsigned int   u32;
typedef __attribute__((ext_vector_type(8))) short short8;   // 8 x bf16 bits (4 VGPR)
typedef __attribute__((ext_vector_type(4))) short short4v;  // 4 x bf16 bits (8 B)
typedef __attribute__((ext_vector_type(4))) float f32x4;    // MFMA 16x16 accumulator

// round-to-nearest-even f32 -> bf16 (finite inputs only)
__device__ __forceinline__ u16 f2bf(float f) {
  u32 u = __float_as_uint(f);
  u32 r = (u + 0x7fffu + ((u >> 16) & 1u)) >> 16;
  return (u16)r;
}

// ---------------------------------------------------------------------------
// Weight pre-convert: qkv_w [768][256] fp32 -> bf16, proj_w [256][256] -> bf16
// ---------------------------------------------------------------------------
__global__ __launch_bounds__(256) void wcvt_kernel(
    const float* __restrict__ qkvw, const float* __restrict__ pw,
    u16* __restrict__ wq, u16* __restrict__ wp) {
  const int e = (blockIdx.x * 256 + threadIdx.x) * 4;  // 256 blocks -> 262144
  if (e < 196608) {
    const float4 v = *(const float4*)(qkvw + e);
    short4v o; o[0]=(short)f2bf(v.x); o[1]=(short)f2bf(v.y);
    o[2]=(short)f2bf(v.z); o[3]=(short)f2bf(v.w);
    *(short4v*)(wq + e) = o;
  } else {
    const int e2 = e - 196608;
    const float4 v = *(const float4*)(pw + e2);
    short4v o; o[0]=(short)f2bf(v.x); o[1]=(short)f2bf(v.y);
    o[2]=(short)f2bf(v.z); o[3]=(short)f2bf(v.w);
    *(short4v*)(wp + e2) = o;
  }
}

// ---------------------------------------------------------------------------
// CPB MLP: table[225][8] = relu(coords @ w1^T + b1) @ w2^T   (fp32 math)
// ---------------------------------------------------------------------------
__global__ __launch_bounds__(256) void cpb_kernel(
    const float* __restrict__ ct, const float* __restrict__ w1,
    const float* __restrict__ b1, const float* __restrict__ w2,
    float* __restrict__ table) {
  const int r = blockIdx.x;            // 0..224
  const int t = threadIdx.x;           // 0..255
  const int lane = t & 63, wave = t >> 6;
  const float c0 = ct[r * 2 + 0];
  const float c1 = ct[r * 2 + 1];
  float acc[8] = {0.f, 0.f, 0.f, 0.f, 0.f, 0.f, 0.f, 0.f};
  for (int j = t; j < 512; j += 256) {
    float hid = fmaxf(c0 * w1[j * 2] + c1 * w1[j * 2 + 1] + b1[j], 0.f);
#pragma unroll
    for (int hh = 0; hh < 8; ++hh) acc[hh] += hid * w2[hh * 512 + j];
  }
#pragma unroll
  for (int hh = 0; hh < 8; ++hh)
#pragma unroll
    for (int off = 1; off < 64; off <<= 1) acc[hh] += __shfl_xor(acc[hh], off);
  __shared__ float red[4][8];
  if (lane == 0)
#pragma unroll
    for (int hh = 0; hh < 8; ++hh) red[wave][hh] = acc[hh];
  __syncthreads();
  if (t < 8) table[r * 8 + t] = red[0][t] + red[1][t] + red[2][t] + red[3][t];
}

// ---------------------------------------------------------------------------
// bmP[w][h][m][l][j] = 16*sigmoid(table[rel[m*64 + j*16+l]][h]) + mask[w][m][j*16+l]
// Permuted so a softmax lane (l15) reads its 4 values as ONE float4.
// fp32, 64*8*64*64 = 8 MB.
// ---------------------------------------------------------------------------
__global__ __launch_bounds__(256) void bm_kernel(
    const float* __restrict__ table, const int* __restrict__ rel,
    const float* __restrict__ mask, float* __restrict__ bmP) {
  const int g = blockIdx.x * 256 + threadIdx.x;   // 0..524287
  const int w = g >> 13;
  const int h = (g >> 10) & 7;
  const int m = (g >> 4) & 63;
  const int l = g & 15;
  float4 o;
#pragma unroll
  for (int j = 0; j < 4; ++j) {
    const int c = j * 16 + l;
    const float t = table[rel[m * 64 + c] * 8 + h];
    o[j] = 16.f / (1.f + __expf(-t)) + mask[(size_t)w * 4096 + m * 64 + c];
  }
  *(float4*)(bmP + ((((size_t)w * 8 + h) * 64 + m) * 64 + l * 4)) = o;
}

// ---------------------------------------------------------------------------
// Fused per-window kernel, WAVE = HEAD structure (512 threads, 8 waves).
// Phase A: cooperative x -> bf16 LDS staging. barrier.
// Phase B+C (one long WAVE-PRIVATE stretch, no cross-wave sync):
//   wave h computes QKV cols {h*32, 256+h*32, 512+h*32} (192 MFMA, each
//   weight row still read exactly once per block), normalizes q/k rows
//   in-register, stages q/k/vt/P in a per-wave LDS scratch (lgkmcnt-ordered),
//   runs S -> softmax -> PV for its own head.
// barrier. o -> sA (reuses x region). barrier. Phase D: proj GEMM.
// 3 barriers; waves desync across ~80% of the kernel for latency hiding.
// LDS: sA 33792 B + 8 x 13824 B = 144384 B (1 block/CU).
// ---------------------------------------------------------------------------
__global__ __launch_bounds__(512, 2) void fused_kernel(
    const float* __restrict__ X,      // [131072][256] fp32
    const float* __restrict__ bmP,    // [64][8][64][64] fp32 (permuted)
    const float* __restrict__ lsc,    // [8] fp32
    const u16*  __restrict__ Wqb,     // [768][256] bf16
    const float* __restrict__ qb, const float* __restrict__ vbias,
    const u16*  __restrict__ Wpb,     // [256][256] bf16
    const float* __restrict__ pb,     // [256] fp32
    float* __restrict__ out) {        // [131072][256] fp32
  __shared__ __attribute__((aligned(16))) u16 sA[16896];     // x[8][64][32] -> o[64][264]
  __shared__ __attribute__((aligned(16))) u16 sW[8][6912];   // per-wave: vt[32*72] | pbuf[64*72]

  const int bw = blockIdx.x;        // window 0..2047
  const int w  = bw & 63;           // mask window index
  const int tid  = threadIdx.x;
  const int wave = tid >> 6, lane = tid & 63;
  const int l15 = lane & 15, l4 = lane >> 4;
  const int h = wave;               // wave == head

  // ---- Phase A: stage x -> bf16 sA[kf][row][32]
  {
    const int cq  = tid & 7;        // 8 chunks of 4 fp32 = 32 cols
    const int rlo = tid >> 3;       // 0..63
    const float* xrow = X + ((size_t)bw * 64 + rlo) * 256;
#pragma unroll
    for (int kf = 0; kf < 8; ++kf) {
      const float4 xv = *(const float4*)(xrow + kf * 32 + cq * 4);
      short4v t4; t4[0]=(short)f2bf(xv.x); t4[1]=(short)f2bf(xv.y);
      t4[2]=(short)f2bf(xv.z); t4[3]=(short)f2bf(xv.w);
      *(short4v*)&sA[kf * 2048 + rlo * 32 + cq * 4] = t4;
    }
  }
  __syncthreads();

  u16* vt   = &sW[wave][0];      // [32][72] transposed V for this head
  u16* pbuf = &sW[wave][2304];   // [64][72] P; q-stage at +0, k-stage at +2048

  f32x4 oa[4][2];                // PV result, written to sA after barrier #2

  // ================= wave-private B+C stretch =================
  {
    // ---- Phase B: QKV GEMM for head h: 6 n-tiles x 4 m-tiles x K=256
    const int rb[6] = {h * 32, h * 32 + 16, 256 + h * 32, 256 + h * 32 + 16,
                       512 + h * 32, 512 + h * 32 + 16};
    f32x4 acc[4][6];
#pragma unroll
    for (int mi = 0; mi < 4; ++mi)
#pragma unroll
      for (int nj = 0; nj < 6; ++nj) acc[mi][nj] = (f32x4){0.f, 0.f, 0.f, 0.f};

    short8 bf_cur[6];
#pragma unroll
    for (int nj = 0; nj < 6; ++nj)
      bf_cur[nj] = *(const short8*)(Wqb + (size_t)(rb[nj] + l15) * 256 + l4 * 8);

#pragma unroll
    for (int kf = 0; kf < 8; ++kf) {
      short8 af[4];
#pragma unroll
      for (int mi = 0; mi < 4; ++mi)
        af[mi] = *(const short8*)&sA[kf * 2048 + (mi * 16 + l15) * 32 + l4 * 8];
      short8 bf_nxt[6];
      if (kf < 7) {
#pragma unroll
        for (int nj = 0; nj < 6; ++nj)
          bf_nxt[nj] = *(const short8*)(Wqb + (size_t)(rb[nj] + l15) * 256 + (kf + 1) * 32 + l4 * 8);
      }
#pragma unroll
      for (int nj = 0; nj < 6; ++nj)
#pragma unroll
        for (int mi = 0; mi < 4; ++mi)
          acc[mi][nj] = __builtin_amdgcn_mfma_f32_16x16x32_bf16(af[mi], bf_cur[nj], acc[mi][nj], 0, 0, 0);
      if (kf < 7) {
#pragma unroll
        for (int nj = 0; nj < 6; ++nj) bf_cur[nj] = bf_nxt[nj];
      }
    }

    // ---- epilogue: Q normalize -> q-stage, K normalize -> k-stage, V -> vt
    u16* qstage = pbuf;            // [64][32]
    u16* kstage = pbuf + 2048;     // [64][32]
    {
      const float qb0 = qb[h * 32 + l15];
      const float qb1 = qb[h * 32 + 16 + l15];
#pragma unroll
      for (int mi = 0; mi < 4; ++mi)
#pragma unroll
        for (int r = 0; r < 4; ++r) {
          const float v0 = acc[mi][0][r] + qb0;
          const float v1 = acc[mi][1][r] + qb1;
          float ss = v0 * v0 + v1 * v1;
          ss += __shfl_xor(ss, 1); ss += __shfl_xor(ss, 2);
          ss += __shfl_xor(ss, 4); ss += __shfl_xor(ss, 8);
          const float inv = 1.f / fmaxf(sqrtf(ss), 1e-12f);
          const int m = mi * 16 + l4 * 4 + r;
          qstage[m * 32 + l15]      = f2bf(v0 * inv);
          qstage[m * 32 + 16 + l15] = f2bf(v1 * inv);
        }
#pragma unroll
      for (int mi = 0; mi < 4; ++mi)
#pragma unroll
        for (int r = 0; r < 4; ++r) {
          const float v0 = acc[mi][2][r];
          const float v1 = acc[mi][3][r];
          float ss = v0 * v0 + v1 * v1;
          ss += __shfl_xor(ss, 1); ss += __shfl_xor(ss, 2);
          ss += __shfl_xor(ss, 4); ss += __shfl_xor(ss, 8);
          const float inv = 1.f / fmaxf(sqrtf(ss), 1e-12f);
          const int m = mi * 16 + l4 * 4 + r;
          kstage[m * 32 + l15]      = f2bf(v0 * inv);
          kstage[m * 32 + 16 + l15] = f2bf(v1 * inv);
        }
      const float vb0 = vbias[h * 32 + l15];
      const float vb1 = vbias[h * 32 + 16 + l15];
#pragma unroll
      for (int mi = 0; mi < 4; ++mi)
#pragma unroll
        for (int r = 0; r < 4; ++r) {
          const int m = mi * 16 + l4 * 4 + r;
          vt[l15 * 72 + m]        = f2bf(acc[mi][4][r] + vb0);
          vt[(16 + l15) * 72 + m] = f2bf(acc[mi][5][r] + vb1);
        }
    }

    // ---- Phase C: attention for head h (all wave-private, lgkmcnt-ordered)
    // bias+mask float4 loads issued first to hide L2/L3 under frag reads+MFMA
    const float* bmbase = bmP + (((size_t)(w * 8 + h)) * 64) * 64 + l15 * 4;
    float4 bmv[4][4];
#pragma unroll
    for (int i = 0; i < 4; ++i)
#pragma unroll
      for (int r = 0; r < 4; ++r) {
        const int m = i * 16 + l4 * 4 + r;
        bmv[i][r] = *(const float4*)(bmbase + (size_t)m * 64);
      }

    short8 aq[4], bk[4];
#pragma unroll
    for (int i = 0; i < 4; ++i)
      aq[i] = *(const short8*)&qstage[(i * 16 + l15) * 32 + l4 * 8];
#pragma unroll
    for (int j = 0; j < 4; ++j)
      bk[j] = *(const short8*)&kstage[(j * 16 + l15) * 32 + l4 * 8];

    f32x4 s[4][4];
    __builtin_amdgcn_s_setprio(1);
#pragma unroll
    for (int i = 0; i < 4; ++i)
#pragma unroll
      for (int j = 0; j < 4; ++j) {
        const f32x4 z = {0.f, 0.f, 0.f, 0.f};
        s[i][j] = __builtin_amdgcn_mfma_f32_16x16x32_bf16(aq[i], bk[j], z, 0, 0, 0);
      }
    __builtin_amdgcn_s_setprio(0);

    const float scale = __expf(fminf(lsc[h], 4.60517018598809136804f));
    u16* pW = pbuf;                // P overwrites q/k stage (frags already read)

#pragma unroll
    for (int i = 0; i < 4; ++i)
#pragma unroll
      for (int r = 0; r < 4; ++r) {
        const int m = i * 16 + l4 * 4 + r;
        float v0[4]; float mx = -3.0e38f;
#pragma unroll
        for (int j = 0; j < 4; ++j) {
          const float sv = s[i][j][r] * scale + bmv[i][r][j];
          v0[j] = sv; mx = fmaxf(mx, sv);
        }
        mx = fmaxf(mx, __shfl_xor(mx, 1)); mx = fmaxf(mx, __shfl_xor(mx, 2));
        mx = fmaxf(mx, __shfl_xor(mx, 4)); mx = fmaxf(mx, __shfl_xor(mx, 8));
        float sum = 0.f;
#pragma unroll
        for (int j = 0; j < 4; ++j) { v0[j] = __expf(v0[j] - mx); sum += v0[j]; }
        sum += __shfl_xor(sum, 1); sum += __shfl_xor(sum, 2);
        sum += __shfl_xor(sum, 4); sum += __shfl_xor(sum, 8);
        const float isum = 1.f / sum;
#pragma unroll
        for (int j = 0; j < 4; ++j)
          pW[m * 72 + j * 16 + l15] = f2bf(v0[j] * isum);
      }

    // O = P @ V : 4 m-tiles x 2 d-tiles x 2 k-steps (wave-private LDS)
#pragma unroll
    for (int i = 0; i < 4; ++i)
#pragma unroll
      for (int nb = 0; nb < 2; ++nb) oa[i][nb] = (f32x4){0.f, 0.f, 0.f, 0.f};
#pragma unroll
    for (int kb = 0; kb < 2; ++kb) {
      short8 pa[4];
#pragma unroll
      for (int i = 0; i < 4; ++i)
        pa[i] = *(const short8*)&pW[(i * 16 + l15) * 72 + kb * 32 + l4 * 8];
      __builtin_amdgcn_s_setprio(1);
#pragma unroll
      for (int nb = 0; nb < 2; ++nb) {
        const short8 vb8 = *(const short8*)&vt[(nb * 16 + l15) * 72 + kb * 32 + l4 * 8];
#pragma unroll
        for (int i = 0; i < 4; ++i)
          oa[i][nb] = __builtin_amdgcn_mfma_f32_16x16x32_bf16(pa[i], vb8, oa[i][nb], 0, 0, 0);
      }
      __builtin_amdgcn_s_setprio(0);
    }
  }
  // ================= end wave-private stretch =================

  __syncthreads();   // all waves done reading sA (x) -> safe to overwrite with o

#pragma unroll
  for (int i = 0; i < 4; ++i)
#pragma unroll
    for (int nb = 0; nb < 2; ++nb)
#pragma unroll
      for (int r = 0; r < 4; ++r) {
        const int m = i * 16 + l4 * 4 + r;
        sA[m * 264 + h * 32 + nb * 16 + l15] = f2bf(oa[i][nb][r]);
      }
  __syncthreads();   // o complete across all waves

  // ---- Phase D: proj. wave owns output cols [wave*32, wave*32+32), K=256
  {
    const int n0 = wave * 32;
    const u16* pbase = Wpb + (size_t)(n0 + l15) * 256 + l4 * 8;
    f32x4 pacc[4][2];
#pragma unroll
    for (int mi = 0; mi < 4; ++mi)
#pragma unroll
      for (int nj = 0; nj < 2; ++nj) pacc[mi][nj] = (f32x4){0.f, 0.f, 0.f, 0.f};

    short8 bfr_cur[2];
#pragma unroll
    for (int nj = 0; nj < 2; ++nj)
      bfr_cur[nj] = *(const short8*)(pbase + (size_t)(nj * 16) * 256);

#pragma unroll
    for (int ks = 0; ks < 8; ++ks) {
      const int k0 = ks * 32;
      short8 afr[4];
#pragma unroll
      for (int mi = 0; mi < 4; ++mi)
        afr[mi] = *(const short8*)&sA[(mi * 16 + l15) * 264 + k0 + l4 * 8];
      short8 bfr_nxt[2];
      if (ks < 7) {
#pragma unroll
        for (int nj = 0; nj < 2; ++nj)
          bfr_nxt[nj] = *(const short8*)(pbase + (size_t)(nj * 16) * 256 + k0 + 32);
      }
#pragma unroll
      for (int nj = 0; nj < 2; ++nj)
#pragma unroll
        for (int mi = 0; mi < 4; ++mi)
          pacc[mi][nj] = __builtin_amdgcn_mfma_f32_16x16x32_bf16(afr[mi], bfr_cur[nj], pacc[mi][nj], 0, 0, 0);
      if (ks < 7) {
#pragma unroll
        for (int nj = 0; nj < 2; ++nj) bfr_cur[nj] = bfr_nxt[nj];
      }
    }
    float* orow = out + (size_t)bw * 64 * 256;
#pragma unroll
    for (int mi = 0; mi < 4; ++mi)
#pragma unroll
      for (int nj = 0; nj < 2; ++nj) {
        const int n = n0 + nj * 16 + l15;
        const float bias = pb[n];
#pragma unroll
        for (int r = 0; r < 4; ++r) {
          const int m = mi * 16 + l4 * 4 + r;
          orow[(size_t)m * 256 + n] = pacc[mi][nj][r] + bias;
        }
      }
  }
}

// ---------------------------------------------------------------------------
// ws layout: [0,16K) table | [256K,640K) Wqkv bf16 | [704K,832K) Wproj bf16 |
// [1M, 9M) bmP fp32.
// ---------------------------------------------------------------------------
extern "C" void kernel_launch(void* const* d_in, const int* in_sizes, int n_in,
                              void* d_out, int out_size, void* d_ws, size_t ws_size,
                              hipStream_t stream) {
  (void)in_sizes; (void)n_in; (void)out_size; (void)ws_size;
  const float* x    = (const float*)d_in[0];
  const float* mask = (const float*)d_in[1];
  const float* qkvw = (const float*)d_in[2];
  const float* qb   = (const float*)d_in[3];
  const float* vb   = (const float*)d_in[4];
  const float* lsc  = (const float*)d_in[5];
  const float* w1   = (const float*)d_in[6];
  const float* b1   = (const float*)d_in[7];
  const float* w2   = (const float*)d_in[8];
  const float* pw   = (const float*)d_in[9];
  const float* pb   = (const float*)d_in[10];
  const float* ct   = (const float*)d_in[11];
  const int* rel    = (const int*)d_in[12];
  float* out = (float*)d_out;

  char* ws = (char*)d_ws;
  float* table = (float*)(ws);
  u16* Wqb = (u16*)(ws + 262144);   // 393,216 B
  u16* Wpb = (u16*)(ws + 720896);   // 131,072 B
  float* bmP = (float*)(ws + (1 << 20));  // 8 MB

  wcvt_kernel<<<256, 256, 0, stream>>>(qkvw, pw, Wqb, Wpb);
  cpb_kernel<<<225, 256, 0, stream>>>(ct, w1, b1, w2, table);
  bm_kernel<<<2048, 256, 0, stream>>>(table, rel, mask, bmP);
  fused_kernel<<<2048, 512, 0, stream>>>(x, bmP, lsc, Wqb, qb, vb,
                                         Wpb, pb, out);
}

// Round 5
// 466.735 us; speedup vs baseline: 1.1995x; 1.0132x over previous
//
#include <hip/hip_runtime.h>
#include <hip/hip_bf16.h>

typedef unsigned short u16;
typedef unsigned int   u32;
typedef __attribute__((ext_vector_type(8))) short short8;   // 8 x bf16 bits (4 VGPR)
typedef __attribute__((ext_vector_type(4))) short short4v;  // 4 x bf16 bits (8 B)
typedef __attribute__((ext_vector_type(4))) float f32x4;    // MFMA 16x16 accumulator

// round-to-nearest-even f32 -> bf16 (finite inputs only)
__device__ __forceinline__ u16 f2bf(float f) {
  u32 u = __float_as_uint(f);
  u32 r = (u + 0x7fffu + ((u >> 16) & 1u)) >> 16;
  return (u16)r;
}

// ---------------------------------------------------------------------------
// Weight pre-convert: qkv_w [768][256] fp32 -> bf16, proj_w [256][256] -> bf16
// ---------------------------------------------------------------------------
__global__ __launch_bounds__(256) void wcvt_kernel(
    const float* __restrict__ qkvw, const float* __restrict__ pw,
    u16* __restrict__ wq, u16* __restrict__ wp) {
  const int e = (blockIdx.x * 256 + threadIdx.x) * 4;  // 256 blocks -> 262144
  if (e < 196608) {
    const float4 v = *(const float4*)(qkvw + e);
    short4v o; o[0]=(short)f2bf(v.x); o[1]=(short)f2bf(v.y);
    o[2]=(short)f2bf(v.z); o[3]=(short)f2bf(v.w);
    *(short4v*)(wq + e) = o;
  } else {
    const int e2 = e - 196608;
    const float4 v = *(const float4*)(pw + e2);
    short4v o; o[0]=(short)f2bf(v.x); o[1]=(short)f2bf(v.y);
    o[2]=(short)f2bf(v.z); o[3]=(short)f2bf(v.w);
    *(short4v*)(wp + e2) = o;
  }
}

// ---------------------------------------------------------------------------
// CPB MLP: table[225][8] = relu(coords @ w1^T + b1) @ w2^T   (fp32 math)
// ---------------------------------------------------------------------------
__global__ __launch_bounds__(256) void cpb_kernel(
    const float* __restrict__ ct, const float* __restrict__ w1,
    const float* __restrict__ b1, const float* __restrict__ w2,
    float* __restrict__ table) {
  const int r = blockIdx.x;            // 0..224
  const int t = threadIdx.x;           // 0..255
  const int lane = t & 63, wave = t >> 6;
  const float c0 = ct[r * 2 + 0];
  const float c1 = ct[r * 2 + 1];
  float acc[8] = {0.f, 0.f, 0.f, 0.f, 0.f, 0.f, 0.f, 0.f};
  for (int j = t; j < 512; j += 256) {
    float hid = fmaxf(c0 * w1[j * 2] + c1 * w1[j * 2 + 1] + b1[j], 0.f);
#pragma unroll
    for (int hh = 0; hh < 8; ++hh) acc[hh] += hid * w2[hh * 512 + j];
  }
#pragma unroll
  for (int hh = 0; hh < 8; ++hh)
#pragma unroll
    for (int off = 1; off < 64; off <<= 1) acc[hh] += __shfl_xor(acc[hh], off);
  __shared__ float red[4][8];
  if (lane == 0)
#pragma unroll
    for (int hh = 0; hh < 8; ++hh) red[wave][hh] = acc[hh];
  __syncthreads();
  if (t < 8) table[r * 8 + t] = red[0][t] + red[1][t] + red[2][t] + red[3][t];
}

// ---------------------------------------------------------------------------
// bmP[w][h][m][l][j] = 16*sigmoid(table[rel[m*64 + j*16+l]][h]) + mask[w][m][j*16+l]
// Permuted so a softmax lane (l15) reads its 4 values as ONE float4.
// fp32, 64*8*64*64 = 8 MB.
// ---------------------------------------------------------------------------
__global__ __launch_bounds__(256) void bm_kernel(
    const float* __restrict__ table, const int* __restrict__ rel,
    const float* __restrict__ mask, float* __restrict__ bmP) {
  const int g = blockIdx.x * 256 + threadIdx.x;   // 0..524287
  const int w = g >> 13;
  const int h = (g >> 10) & 7;
  const int m = (g >> 4) & 63;
  const int l = g & 15;
  float4 o;
#pragma unroll
  for (int j = 0; j < 4; ++j) {
    const int c = j * 16 + l;
    const float t = table[rel[m * 64 + c] * 8 + h];
    o[j] = 16.f / (1.f + __expf(-t)) + mask[(size_t)w * 4096 + m * 64 + c];
  }
  *(float4*)(bmP + ((((size_t)w * 8 + h) * 64 + m) * 64 + l * 4)) = o;
}

// ---------------------------------------------------------------------------
// Fused per-window kernel, WAVE-PAIR = HEAD (1024 threads, 16 waves).
// wave = (h = wave>>1, half = wave&1):
//   half0 owns Q rows (2 w-tiles) + V tile0 of head h
//   half1 owns K rows (2 w-tiles) + V tile1 of head h
// -> QKV weights read EXACTLY once per block (no round-2 duplication), but
// 4 waves/SIMD (occupancy ~46%) and halved per-wave dependency chains.
// Phases: A stage x (barrier) | B QKV GEMM + norm/stage epilogue (barrier)
//         | C1 S-MFMA (barrier: q/k stage consumed -> P may overwrite)
//         | C2 softmax + PV -> o in sA (barrier) | D proj.
// LDS: sA 33792 B + 8 heads x 13824 B = 144384 B (1 block/CU).
// ---------------------------------------------------------------------------
__global__ __launch_bounds__(1024) void fused_kernel(
    const float* __restrict__ X,      // [131072][256] fp32
    const float* __restrict__ bmP,    // [64][8][64][64] fp32 (permuted)
    const float* __restrict__ lsc,    // [8] fp32
    const u16*  __restrict__ Wqb,     // [768][256] bf16
    const float* __restrict__ qb, const float* __restrict__ vbias,
    const u16*  __restrict__ Wpb,     // [256][256] bf16
    const float* __restrict__ pb,     // [256] fp32
    float* __restrict__ out) {        // [131072][256] fp32
  __shared__ __attribute__((aligned(16))) u16 sA[16896];     // x[8][64][32] -> o[64][264]
  __shared__ __attribute__((aligned(16))) u16 sW[8][6912];   // per-head: vt[2304] | pq[2048]+pk[2048] -> P[64][72]

  const int bw = blockIdx.x;        // window 0..2047
  const int w  = bw & 63;           // mask window index
  const int tid  = threadIdx.x;
  const int wave = tid >> 6, lane = tid & 63;
  const int l15 = lane & 15, l4 = lane >> 4;
  const int h    = wave >> 1;       // head
  const int half = wave & 1;        // 0: Q+V0, 1: K+V1

  // ---- Phase A: stage x -> bf16 sA[kf][row][32]
  {
    const int row = tid >> 4;       // 0..63
    const int c4  = tid & 15;
    const float* xrow = X + ((size_t)bw * 64 + row) * 256;
#pragma unroll
    for (int u = 0; u < 4; ++u) {
      const int col = u * 64 + c4 * 4;
      const int kf = col >> 5, co = col & 31;
      const float4 xv = *(const float4*)(xrow + col);
      short4v t4; t4[0]=(short)f2bf(xv.x); t4[1]=(short)f2bf(xv.y);
      t4[2]=(short)f2bf(xv.z); t4[3]=(short)f2bf(xv.w);
      *(short4v*)&sA[kf * 2048 + row * 32 + co] = t4;
    }
  }
  __syncthreads();

  u16* vt = &sW[h][0];        // [32][72] V^T (d, token), both halves write
  u16* pq = &sW[h][2304];     // [64][32] normalized Q
  u16* pk = &sW[h][4352];     // [64][32] normalized K
  u16* pP = &sW[h][2304];     // [64][72] P (overwrites pq/pk after barrier 3)

  // ---- Phase B: QKV GEMM. 3 weight row-blocks per wave, all 64 x-rows, K=256
  {
    const int rb0 = half ? (256 + h * 32)      : (h * 32);
    const int rb1 = half ? (256 + h * 32 + 16) : (h * 32 + 16);
    const int rb2 = half ? (512 + h * 32 + 16) : (512 + h * 32);
    const u16* wb0 = Wqb + (size_t)(rb0 + l15) * 256 + l4 * 8;
    const u16* wb1 = Wqb + (size_t)(rb1 + l15) * 256 + l4 * 8;
    const u16* wb2 = Wqb + (size_t)(rb2 + l15) * 256 + l4 * 8;

    f32x4 acc[4][3];
#pragma unroll
    for (int mi = 0; mi < 4; ++mi)
#pragma unroll
      for (int nj = 0; nj < 3; ++nj) acc[mi][nj] = (f32x4){0.f, 0.f, 0.f, 0.f};

    short8 bf_cur[3];
    bf_cur[0] = *(const short8*)wb0;
    bf_cur[1] = *(const short8*)wb1;
    bf_cur[2] = *(const short8*)wb2;

#pragma unroll
    for (int kf = 0; kf < 8; ++kf) {
      short8 af[4];
#pragma unroll
      for (int mi = 0; mi < 4; ++mi)
        af[mi] = *(const short8*)&sA[kf * 2048 + (mi * 16 + l15) * 32 + l4 * 8];
      short8 bf_nxt[3];
      if (kf < 7) {
        bf_nxt[0] = *(const short8*)(wb0 + (kf + 1) * 32);
        bf_nxt[1] = *(const short8*)(wb1 + (kf + 1) * 32);
        bf_nxt[2] = *(const short8*)(wb2 + (kf + 1) * 32);
      }
      __builtin_amdgcn_s_setprio(1);
#pragma unroll
      for (int nj = 0; nj < 3; ++nj)
#pragma unroll
        for (int mi = 0; mi < 4; ++mi)
          acc[mi][nj] = __builtin_amdgcn_mfma_f32_16x16x32_bf16(af[mi], bf_cur[nj], acc[mi][nj], 0, 0, 0);
      __builtin_amdgcn_s_setprio(0);
      if (kf < 7) {
#pragma unroll
        for (int nj = 0; nj < 3; ++nj) bf_cur[nj] = bf_nxt[nj];
      }
    }

    // ---- epilogue: normalize q (half0) / k (half1) rows -> stage; V -> vt
    if (half == 0) {
      const float b0 = qb[h * 32 + l15];
      const float b1 = qb[h * 32 + 16 + l15];
#pragma unroll
      for (int mi = 0; mi < 4; ++mi)
#pragma unroll
        for (int r = 0; r < 4; ++r) {
          const float v0 = acc[mi][0][r] + b0;
          const float v1 = acc[mi][1][r] + b1;
          float ss = v0 * v0 + v1 * v1;
          ss += __shfl_xor(ss, 1); ss += __shfl_xor(ss, 2);
          ss += __shfl_xor(ss, 4); ss += __shfl_xor(ss, 8);
          const float inv = 1.f / fmaxf(sqrtf(ss), 1e-12f);
          const int m = mi * 16 + l4 * 4 + r;
          pq[m * 32 + l15]      = f2bf(v0 * inv);
          pq[m * 32 + 16 + l15] = f2bf(v1 * inv);
        }
      const float vb0 = vbias[h * 32 + l15];
#pragma unroll
      for (int mi = 0; mi < 4; ++mi)
#pragma unroll
        for (int r = 0; r < 4; ++r) {
          const int m = mi * 16 + l4 * 4 + r;
          vt[l15 * 72 + m] = f2bf(acc[mi][2][r] + vb0);
        }
    } else {
#pragma unroll
      for (int mi = 0; mi < 4; ++mi)
#pragma unroll
        for (int r = 0; r < 4; ++r) {
          const float v0 = acc[mi][0][r];
          const float v1 = acc[mi][1][r];
          float ss = v0 * v0 + v1 * v1;
          ss += __shfl_xor(ss, 1); ss += __shfl_xor(ss, 2);
          ss += __shfl_xor(ss, 4); ss += __shfl_xor(ss, 8);
          const float inv = 1.f / fmaxf(sqrtf(ss), 1e-12f);
          const int m = mi * 16 + l4 * 4 + r;
          pk[m * 32 + l15]      = f2bf(v0 * inv);
          pk[m * 32 + 16 + l15] = f2bf(v1 * inv);
        }
      const float vb1 = vbias[h * 32 + 16 + l15];
#pragma unroll
      for (int mi = 0; mi < 4; ++mi)
#pragma unroll
        for (int r = 0; r < 4; ++r) {
          const int m = mi * 16 + l4 * 4 + r;
          vt[(16 + l15) * 72 + m] = f2bf(acc[mi][2][r] + vb1);
        }
    }
  }
  __syncthreads();   // qn/kn/vt complete (x reads also all done)

  // ---- Phase C1: S = Qn.Kn^T for rows [half*32, half*32+32) of head h
  f32x4 s[2][4];
  float4 bmv[2][4];
  {
    // bias+mask loads issued first (independent) to hide L2/L3 latency
    const float* bmbase = bmP + (((size_t)(w * 8 + h)) * 64) * 64 + l15 * 4;
#pragma unroll
    for (int i = 0; i < 2; ++i)
#pragma unroll
      for (int r = 0; r < 4; ++r) {
        const int m = half * 32 + i * 16 + l4 * 4 + r;
        bmv[i][r] = *(const float4*)(bmbase + (size_t)m * 64);
      }

    short8 aq[2], bk[4];
#pragma unroll
    for (int i = 0; i < 2; ++i)
      aq[i] = *(const short8*)&pq[(half * 32 + i * 16 + l15) * 32 + l4 * 8];
#pragma unroll
    for (int j = 0; j < 4; ++j)
      bk[j] = *(const short8*)&pk[(j * 16 + l15) * 32 + l4 * 8];

    __builtin_amdgcn_s_setprio(1);
#pragma unroll
    for (int i = 0; i < 2; ++i)
#pragma unroll
      for (int j = 0; j < 4; ++j) {
        const f32x4 z = {0.f, 0.f, 0.f, 0.f};
        s[i][j] = __builtin_amdgcn_mfma_f32_16x16x32_bf16(aq[i], bk[j], z, 0, 0, 0);
      }
    __builtin_amdgcn_s_setprio(0);
  }
  __syncthreads();   // pq/pk consumed by both pair-waves -> P may overwrite

  // ---- Phase C2: softmax -> P -> PV -> o (wave-private, lgkmcnt-ordered)
  {
    const float scale = __expf(fminf(lsc[h], 4.60517018598809136804f));
#pragma unroll
    for (int i = 0; i < 2; ++i)
#pragma unroll
      for (int r = 0; r < 4; ++r) {
        const int prow = half * 32 + i * 16 + l4 * 4 + r;
        float v0[4]; float mx = -3.0e38f;
#pragma unroll
        for (int j = 0; j < 4; ++j) {
          const float sv = s[i][j][r] * scale + bmv[i][r][j];
          v0[j] = sv; mx = fmaxf(mx, sv);
        }
        mx = fmaxf(mx, __shfl_xor(mx, 1)); mx = fmaxf(mx, __shfl_xor(mx, 2));
        mx = fmaxf(mx, __shfl_xor(mx, 4)); mx = fmaxf(mx, __shfl_xor(mx, 8));
        float sum = 0.f;
#pragma unroll
        for (int j = 0; j < 4; ++j) { v0[j] = __expf(v0[j] - mx); sum += v0[j]; }
        sum += __shfl_xor(sum, 1); sum += __shfl_xor(sum, 2);
        sum += __shfl_xor(sum, 4); sum += __shfl_xor(sum, 8);
        const float isum = 1.f / sum;
#pragma unroll
        for (int j = 0; j < 4; ++j)
          pP[prow * 72 + j * 16 + l15] = f2bf(v0[j] * isum);
      }

    // O = P @ V : 2 m-tiles x 2 d-tiles x 2 k-steps (own P rows, shared vt)
    f32x4 oa[2][2];
#pragma unroll
    for (int i = 0; i < 2; ++i)
#pragma unroll
      for (int nb = 0; nb < 2; ++nb) oa[i][nb] = (f32x4){0.f, 0.f, 0.f, 0.f};
#pragma unroll
    for (int kb = 0; kb < 2; ++kb) {
      short8 pa[2];
#pragma unroll
      for (int i = 0; i < 2; ++i)
        pa[i] = *(const short8*)&pP[(half * 32 + i * 16 + l15) * 72 + kb * 32 + l4 * 8];
      __builtin_amdgcn_s_setprio(1);
#pragma unroll
      for (int nb = 0; nb < 2; ++nb) {
        const short8 vb8 = *(const short8*)&vt[(nb * 16 + l15) * 72 + kb * 32 + l4 * 8];
#pragma unroll
        for (int i = 0; i < 2; ++i)
          oa[i][nb] = __builtin_amdgcn_mfma_f32_16x16x32_bf16(pa[i], vb8, oa[i][nb], 0, 0, 0);
      }
      __builtin_amdgcn_s_setprio(0);
    }
    // o -> sA (x region dead since barrier 2; rows/cols disjoint per wave)
#pragma unroll
    for (int i = 0; i < 2; ++i)
#pragma unroll
      for (int nb = 0; nb < 2; ++nb)
#pragma unroll
        for (int r = 0; r < 4; ++r) {
          const int m = half * 32 + i * 16 + l4 * 4 + r;
          sA[m * 264 + h * 32 + nb * 16 + l15] = f2bf(oa[i][nb][r]);
        }
  }
  __syncthreads();   // o complete across all waves

  // ---- Phase D: proj. wave=(wm=wave&1, wn=wave>>1): rows wm*32+, cols wn*32+
  {
    const int wm = wave & 1;
    const int n0 = (wave >> 1) * 32;
    const u16* pbase = Wpb + (size_t)(n0 + l15) * 256 + l4 * 8;
    f32x4 pacc[2][2];
#pragma unroll
    for (int mi = 0; mi < 2; ++mi)
#pragma unroll
      for (int nj = 0; nj < 2; ++nj) pacc[mi][nj] = (f32x4){0.f, 0.f, 0.f, 0.f};

    short8 bfr_cur[2];
#pragma unroll
    for (int nj = 0; nj < 2; ++nj)
      bfr_cur[nj] = *(const short8*)(pbase + (size_t)(nj * 16) * 256);

#pragma unroll
    for (int ks = 0; ks < 8; ++ks) {
      const int k0 = ks * 32;
      short8 afr[2];
#pragma unroll
      for (int mi = 0; mi < 2; ++mi)
        afr[mi] = *(const short8*)&sA[(wm * 32 + mi * 16 + l15) * 264 + k0 + l4 * 8];
      short8 bfr_nxt[2];
      if (ks < 7) {
#pragma unroll
        for (int nj = 0; nj < 2; ++nj)
          bfr_nxt[nj] = *(const short8*)(pbase + (size_t)(nj * 16) * 256 + k0 + 32);
      }
#pragma unroll
      for (int nj = 0; nj < 2; ++nj)
#pragma unroll
        for (int mi = 0; mi < 2; ++mi)
          pacc[mi][nj] = __builtin_amdgcn_mfma_f32_16x16x32_bf16(afr[mi], bfr_cur[nj], pacc[mi][nj], 0, 0, 0);
      if (ks < 7) {
#pragma unroll
        for (int nj = 0; nj < 2; ++nj) bfr_cur[nj] = bfr_nxt[nj];
      }
    }
    float* orow = out + (size_t)bw * 64 * 256;
#pragma unroll
    for (int mi = 0; mi < 2; ++mi)
#pragma unroll
      for (int nj = 0; nj < 2; ++nj) {
        const int n = n0 + nj * 16 + l15;
        const float bias = pb[n];
#pragma unroll
        for (int r = 0; r < 4; ++r) {
          const int m = wm * 32 + mi * 16 + l4 * 4 + r;
          orow[(size_t)m * 256 + n] = pacc[mi][nj][r] + bias;
        }
      }
  }
}

// ---------------------------------------------------------------------------
// ws layout: [0,16K) table | [256K,640K) Wqkv bf16 | [704K,832K) Wproj bf16 |
// [1M, 9M) bmP fp32.
// ---------------------------------------------------------------------------
extern "C" void kernel_launch(void* const* d_in, const int* in_sizes, int n_in,
                              void* d_out, int out_size, void* d_ws, size_t ws_size,
                              hipStream_t stream) {
  (void)in_sizes; (void)n_in; (void)out_size; (void)ws_size;
  const float* x    = (const float*)d_in[0];
  const float* mask = (const float*)d_in[1];
  const float* qkvw = (const float*)d_in[2];
  const float* qb   = (const float*)d_in[3];
  const float* vb   = (const float*)d_in[4];
  const float* lsc  = (const float*)d_in[5];
  const float* w1   = (const float*)d_in[6];
  const float* b1   = (const float*)d_in[7];
  const float* w2   = (const float*)d_in[8];
  const float* pw   = (const float*)d_in[9];
  const float* pb   = (const float*)d_in[10];
  const float* ct   = (const float*)d_in[11];
  const int* rel    = (const int*)d_in[12];
  float* out = (float*)d_out;

  char* ws = (char*)d_ws;
  float* table = (float*)(ws);
  u16* Wqb = (u16*)(ws + 262144);   // 393,216 B
  u16* Wpb = (u16*)(ws + 720896);   // 131,072 B
  float* bmP = (float*)(ws + (1 << 20));  // 8 MB

  wcvt_kernel<<<256, 256, 0, stream>>>(qkvw, pw, Wqb, Wpb);
  cpb_kernel<<<225, 256, 0, stream>>>(ct, w1, b1, w2, table);
  bm_kernel<<<2048, 256, 0, stream>>>(table, rel, mask, bmP);
  fused_kernel<<<2048, 1024, 0, stream>>>(x, bmP, lsc, Wqb, qb, vb,
                                          Wpb, pb, out);
}